// Round 4
// baseline (1036.669 us; speedup 1.0000x reference)
//
#include <hip/hip_runtime.h>
#include <hip/hip_bf16.h>

#define N_NODES 100000
#define N_EDGES 1600000
#define N_GRAPHS 1024
#define F_NODE 16
#define F_EDGE 8
#define F_GRAPH 10
#define HD 64
#define HD2 128
#define GEN_EPS 1e-7f
#define SCAN_NBLK ((N_NODES + 255) / 256)   // 391
#define AGG_BLK 2048
#define NWAVES (AGG_BLK * 4)                 // 8192
#define KPW ((N_NODES + NWAVES - 1) / NWAVES) // 13 nodes per wave

typedef unsigned short u16;
typedef unsigned int u32;
typedef __attribute__((ext_vector_type(8))) short short8;
typedef __attribute__((ext_vector_type(4))) float floatx4;

__device__ __forceinline__ u16 f2bf(float x) {   // RNE bf16 (finite inputs)
    u32 u = __float_as_uint(x);
    return (u16)((u + 0x7FFFu + ((u >> 16) & 1u)) >> 16);
}
__device__ __forceinline__ float bf2f(u16 u) {
    return __uint_as_float(((u32)u) << 16);
}
__device__ __forceinline__ float u2f(unsigned int u) {
    return __uint_as_float(u);
}

// h[n][f] = node_b[f] + sum_k x[n][k]*node_W[k][f]; also emits bf16 mirror hb.
__global__ void __launch_bounds__(256) k_node_embed(
        const float* __restrict__ x, const float* __restrict__ W,
        const float* __restrict__ b, float* __restrict__ h,
        u16* __restrict__ hb) {
    __shared__ float sW[F_NODE * HD];
    __shared__ float sb[HD];
    for (int i = threadIdx.x; i < F_NODE * HD; i += 256) sW[i] = W[i];
    if (threadIdx.x < HD) sb[threadIdx.x] = b[threadIdx.x];
    __syncthreads();
    int t = blockIdx.x * 256 + threadIdx.x;
    if (t >= N_NODES * HD) return;
    int n = t >> 6, f = t & 63;
    const float* xr = x + (size_t)n * F_NODE;
    float acc = sb[f];
#pragma unroll
    for (int k = 0; k < F_NODE; k++) acc += xr[k] * sW[k * HD + f];
    h[t] = acc;
    hb[t] = f2bf(acc);
}

// ---- CSR build ----
__global__ void __launch_bounds__(256) k_hist(
        const int* __restrict__ dst, int* __restrict__ deg,
        int* __restrict__ rank) {
    int e = blockIdx.x * 256 + threadIdx.x;
    if (e >= N_EDGES) return;
    rank[e] = atomicAdd(&deg[dst[e]], 1);
}

__global__ void __launch_bounds__(256) k_scan1(
        const int* __restrict__ deg, int* __restrict__ bsum) {
    __shared__ int red[256];
    int t = threadIdx.x;
    int g = blockIdx.x * 256 + t;
    red[t] = (g < N_NODES) ? deg[g] : 0;
    __syncthreads();
    for (int s = 128; s > 0; s >>= 1) {
        if (t < s) red[t] += red[t + s];
        __syncthreads();
    }
    if (t == 0) bsum[blockIdx.x] = red[0];
}

__global__ void __launch_bounds__(512) k_scan2(
        const int* __restrict__ bsum, int* __restrict__ bpre) {
    __shared__ int sh[512];
    int t = threadIdx.x;
    int v = (t < SCAN_NBLK) ? bsum[t] : 0;
    sh[t] = v;
    __syncthreads();
    for (int d = 1; d < 512; d <<= 1) {
        int u = (t >= d) ? sh[t - d] : 0;
        __syncthreads();
        sh[t] += u;
        __syncthreads();
    }
    if (t < SCAN_NBLK) bpre[t] = sh[t] - v;   // exclusive
}

__global__ void __launch_bounds__(256) k_scan3(
        const int* __restrict__ deg, const int* __restrict__ bpre,
        int* __restrict__ off) {
    __shared__ int sh[256];
    int t = threadIdx.x;
    int g = blockIdx.x * 256 + t;
    int v = (g < N_NODES) ? deg[g] : 0;
    sh[t] = v;
    __syncthreads();
    for (int d = 1; d < 256; d <<= 1) {
        int u = (t >= d) ? sh[t - d] : 0;
        __syncthreads();
        sh[t] += u;
        __syncthreads();
    }
    int incl = sh[t];
    int base = bpre[blockIdx.x];
    if (g < N_NODES) off[g] = base + incl - v;
    if (g == N_NODES - 1) off[N_NODES] = base + incl;
}

// Scatter edge attrs (verbatim) + separate srcs[] array.
__global__ void __launch_bounds__(256) k_scatter(
        const int* __restrict__ src, const int* __restrict__ dst,
        const int* __restrict__ rank, const int* __restrict__ off,
        const float* __restrict__ eattr,
        unsigned int* __restrict__ rec, int* __restrict__ srcs) {
    int e = blockIdx.x * 256 + threadIdx.x;
    if (e >= N_EDGES) return;
    const uint4* ap = reinterpret_cast<const uint4*>(eattr + (size_t)e * F_EDGE);
    uint4 a0 = ap[0], a1 = ap[1];           // coalesced 32B read
    int pos = off[dst[e]] + rank[e];
    uint4* op = reinterpret_cast<uint4*>(rec + (size_t)pos * 8);
    op[0] = a0;                              // one 32B sector
    op[1] = a1;
    srcs[pos] = src[e];
}

// ---- GENConv aggregation (pipelined, contiguous node ranges) ----
// Each wave owns KPW consecutive nodes. One per-lane load fetches ALL the
// wave's CSR offsets (off[nbeg..nbeg+KPW], <=14 ints). Per node:
//   - srcs vector (one per-lane 256B load, covers <=64 edges) and h-row
//     were prefetched LAST iteration -> ready at node start.
//   - all <=32 hb gathers issued immediately (readlane of srcs vec).
//   - next node's srcs/h issued right after -> cross-node overlap.
//   - rec attrs via uniform s_load chunks (proven path), full-8 chunks;
//     overrun lands in this wave's own next node (contiguous) = prefetch.
// Single dependent memory epoch per node instead of three.
__global__ void __launch_bounds__(256) k_gen_agg(
        const float* __restrict__ h, const u16* __restrict__ hb,
        const int* __restrict__ off,
        const unsigned int* __restrict__ rec,
        const int* __restrict__ srcs,
        const float* __restrict__ eW, const float* __restrict__ eb,
        float* __restrict__ outb) {
    int lane = threadIdx.x & 63;
    int f = lane;
    float w[F_EDGE];
#pragma unroll
    for (int k = 0; k < F_EDGE; k++) w[k] = eW[k * HD + f];
    float bf = eb[f];
    int wv = blockIdx.x * 4 + (threadIdx.x >> 6);
    int nbeg = wv * KPW;
    if (nbeg >= N_NODES) return;
    int nend = nbeg + KPW;
    if (nend > N_NODES) nend = N_NODES;
    int cnt = nend - nbeg;
    // all offsets for this wave in one coalesced load
    int oidx = nbeg + lane;
    if (oidx > N_NODES) oidx = N_NODES;
    int offv = off[oidx];
    // prefetch node 0
    int beg = __builtin_amdgcn_readlane(offv, 0);
    int end = __builtin_amdgcn_readlane(offv, 1);
    int sv = srcs[beg + lane];                     // padded by 64 at array end
    float hroot = h[(size_t)nbeg * HD + f];
    for (int j = 0; j < cnt; j++) {
        int n = nbeg + j;
        int deg = end - beg;
        // issue all gathers for up to 32 edges (groups of 8, uniform guards)
        float hv[32];
#pragma unroll
        for (int g8 = 0; g8 < 4; g8++) {
            if (g8 * 8 < deg) {
#pragma unroll
                for (int u = 0; u < 8; u++) {
                    int s = __builtin_amdgcn_readlane(sv, g8 * 8 + u);
                    hv[g8 * 8 + u] = bf2f(hb[(size_t)s * HD + f]);
                }
            }
        }
        // prefetch next node (srcs vec + h row) while gathers are in flight
        int endN = 0, svN = 0;
        float hrootN = 0.f;
        if (j + 1 < cnt) {
            endN = __builtin_amdgcn_readlane(offv, j + 2);
            svN = srcs[end + lane];
            hrootN = h[(size_t)(n + 1) * HD + f];
        }
        float den = 0.f, nm = 0.f;
#pragma unroll
        for (int c = 0; c < 4; c++) {
            int i0 = beg + c * 8;
            if (i0 < end) {
                uint4 q0[8], q1[8];
#pragma unroll
                for (int u = 0; u < 8; u++) {
                    const uint4* rp = reinterpret_cast<const uint4*>(
                        rec + (size_t)(i0 + u) * 8);
                    q0[u] = rp[0];
                    q1[u] = rp[1];
                }
#pragma unroll
                for (int u = 0; u < 8; u++) {
                    if (i0 + u < end) {
                        float ea = bf + u2f(q0[u].x) * w[0] + u2f(q0[u].y) * w[1]
                                      + u2f(q0[u].z) * w[2] + u2f(q0[u].w) * w[3]
                                      + u2f(q1[u].x) * w[4] + u2f(q1[u].y) * w[5]
                                      + u2f(q1[u].z) * w[6] + u2f(q1[u].w) * w[7];
                        float r = fmaxf(hv[c * 8 + u] + ea, 0.f);
                        float ev = __expf(r);
                        den += ev;
                        nm += r * ev;
                    }
                }
            }
        }
        // rare tail: degree > 32 (P ~ 1e-4 for this graph)
        for (int i = beg + 32; i < end; i++) {
            int s = srcs[i];
            float hvv = bf2f(hb[(size_t)s * HD + f]);
            const uint4* rp = reinterpret_cast<const uint4*>(rec + (size_t)i * 8);
            uint4 q0 = rp[0], q1 = rp[1];
            float ea = bf + u2f(q0.x) * w[0] + u2f(q0.y) * w[1]
                          + u2f(q0.z) * w[2] + u2f(q0.w) * w[3]
                          + u2f(q1.x) * w[4] + u2f(q1.y) * w[5]
                          + u2f(q1.z) * w[6] + u2f(q1.w) * w[7];
            float r = fmaxf(hvv + ea, 0.f);
            float ev = __expf(r);
            den += ev;
            nm += r * ev;
        }
        float agg = (deg > 0) ? (nm / fmaxf(den, 1e-16f) + GEN_EPS) : 0.f;
        outb[(size_t)n * HD + f] = hroot + agg;
        beg = end;
        end = endN;
        sv = svN;
        hroot = hrootN;
    }
}

// ---- Fused MLP (MFMA): hid = relu(in@W1+b1) staged in LDS, then
// h' = relu(hid@W2+b2).
__global__ void __launch_bounds__(256) k_mlp(
        const float* __restrict__ inb,
        const float* __restrict__ W1, const float* __restrict__ b1,
        const float* __restrict__ W2, const float* __restrict__ b2,
        float* __restrict__ hout, u16* __restrict__ hbout) {
    __shared__ u16 wB1[HD2][HD + 8];    // [j][k], 18.4 KB
    __shared__ u16 wB2[HD][HD2 + 8];    // [c][j], 17.4 KB
    __shared__ u16 sHid[64][HD2 + 8];   // [local n][j], 17.4 KB
    __shared__ float sb1[HD2];
    __shared__ float sb2[HD];
    int tid = threadIdx.x;
    for (int i = tid; i < HD * HD2; i += 256) {
        int ff = i >> 7, j = i & 127;
        wB1[j][ff] = f2bf(W1[i]);
    }
    for (int i = tid; i < HD2 * HD; i += 256) {
        int j = i >> 6, c = i & 63;
        wB2[c][j] = f2bf(W2[i]);
    }
    if (tid < HD2) sb1[tid] = b1[tid];
    if (tid < HD) sb2[tid] = b2[tid];
    __syncthreads();
    int wid = tid >> 6, lane = tid & 63;
    int quad = lane >> 4, lm = lane & 15;
    int n0 = blockIdx.x * 64 + wid * 16;
    bool active = (n0 < N_NODES);         // 100000 % 16 == 0: whole-tile guard
    if (active) {
        int node = n0 + lm;
        short8 a[2];
        const float* ar = inb + (size_t)node * HD;
#pragma unroll
        for (int kk = 0; kk < 2; kk++) {
            const float4* p = reinterpret_cast<const float4*>(ar + kk * 32 + quad * 8);
            float4 v0 = p[0], v1 = p[1];
            short8 t;
            t[0] = (short)f2bf(v0.x); t[1] = (short)f2bf(v0.y);
            t[2] = (short)f2bf(v0.z); t[3] = (short)f2bf(v0.w);
            t[4] = (short)f2bf(v1.x); t[5] = (short)f2bf(v1.y);
            t[6] = (short)f2bf(v1.z); t[7] = (short)f2bf(v1.w);
            a[kk] = t;
        }
#pragma unroll
        for (int jt = 0; jt < 8; jt++) {
            int jb = jt * 16;
            float bias = sb1[jb + lm];
            floatx4 acc = {bias, bias, bias, bias};
#pragma unroll
            for (int kk = 0; kk < 2; kk++) {
                const short8* bp = reinterpret_cast<const short8*>(
                    &wB1[jb + lm][kk * 32 + quad * 8]);
                acc = __builtin_amdgcn_mfma_f32_16x16x32_bf16(a[kk], *bp, acc, 0, 0, 0);
            }
#pragma unroll
            for (int r = 0; r < 4; r++) {
                int lr = wid * 16 + quad * 4 + r;
                sHid[lr][jb + lm] = f2bf(fmaxf(acc[r], 0.f));
            }
        }
    }
    __syncthreads();
    if (active) {
        short8 a2[4];
#pragma unroll
        for (int kk = 0; kk < 4; kk++)
            a2[kk] = *reinterpret_cast<const short8*>(
                &sHid[wid * 16 + lm][kk * 32 + quad * 8]);
#pragma unroll
        for (int ct = 0; ct < 4; ct++) {
            int cb = ct * 16;
            float bias = sb2[cb + lm];
            floatx4 acc = {bias, bias, bias, bias};
#pragma unroll
            for (int kk = 0; kk < 4; kk++) {
                const short8* bp = reinterpret_cast<const short8*>(
                    &wB2[cb + lm][kk * 32 + quad * 8]);
                acc = __builtin_amdgcn_mfma_f32_16x16x32_bf16(a2[kk], *bp, acc, 0, 0, 0);
            }
#pragma unroll
            for (int r = 0; r < 4; r++) {
                int orow = n0 + quad * 4 + r;
                float o = fmaxf(acc[r], 0.f);
                hout[(size_t)orow * HD + cb + lm] = o;
                hbout[(size_t)orow * HD + cb + lm] = f2bf(o);
            }
        }
    }
}

// One wave per graph; range via inline binary search on sorted batch.
__global__ void __launch_bounds__(256) k_pool(
        const float* __restrict__ h, const int* __restrict__ batch,
        float* __restrict__ pooled) {
    int g = blockIdx.x * 4 + (threadIdx.x >> 6);
    if (g >= N_GRAPHS) return;
    int f = threadIdx.x & 63;
    int lo = 0, hi = N_NODES;
    while (lo < hi) {
        int mid = (lo + hi) >> 1;
        if (batch[mid] < g) lo = mid + 1; else hi = mid;
    }
    int b = lo;
    int lo2 = b, hi2 = N_NODES;
    while (lo2 < hi2) {
        int mid = (lo2 + hi2) >> 1;
        if (batch[mid] < g + 1) lo2 = mid + 1; else hi2 = mid;
    }
    int e = lo2;
    float s = 0.f;
    for (int n = b; n < e; n++) s += h[(size_t)n * HD + f];
    float cnt = fmaxf((float)(e - b), 1.f);
    pooled[(size_t)g * HD + f] = s / cnt;
}

__global__ void __launch_bounds__(64) k_head(
        const float* __restrict__ pooled, const float* __restrict__ gattr,
        const float* __restrict__ d1W, const float* __restrict__ d1b,
        const float* __restrict__ d2W, const float* __restrict__ d2b,
        const float* __restrict__ oW, const float* __restrict__ ob,
        float* __restrict__ out) {
    int g = blockIdx.x;
    __shared__ float si[HD + F_GRAPH];
    __shared__ float s1[32], s2[32];
    int t = threadIdx.x;
    if (t < HD) si[t] = pooled[(size_t)g * HD + t];
    if (t < F_GRAPH) si[HD + t] = gattr[(size_t)g * F_GRAPH + t];
    __syncthreads();
    if (t < 32) {
        float acc = d1b[t];
        for (int i = 0; i < HD + F_GRAPH; i++) acc += si[i] * d1W[i * 32 + t];
        s1[t] = fmaxf(acc, 0.f);
    }
    __syncthreads();
    if (t < 32) {
        float acc = d2b[t];
        for (int i = 0; i < 32; i++) acc += s1[i] * d2W[i * 32 + t];
        s2[t] = fmaxf(acc, 0.f);
    }
    __syncthreads();
    if (t == 0) {
        float acc = ob[0];
        for (int i = 0; i < 32; i++) acc += s2[i] * oW[i];
        out[g] = 1.f / (1.f + __expf(-acc));
    }
}

extern "C" void kernel_launch(void* const* d_in, const int* in_sizes, int n_in,
                              void* d_out, int out_size, void* d_ws, size_t ws_size,
                              hipStream_t stream) {
    const float* x     = (const float*)d_in[0];
    const float* eattr = (const float*)d_in[1];
    const float* gattr = (const float*)d_in[2];
    const int*   eidx  = (const int*)d_in[3];
    const int*   batch = (const int*)d_in[4];
    const float* nodeW = (const float*)d_in[5];
    const float* nodeb = (const float*)d_in[6];
    const float* edgeW = (const float*)d_in[7];
    const float* edgeb = (const float*)d_in[8];
    const float* cW1[3] = {(const float*)d_in[9],  (const float*)d_in[13], (const float*)d_in[17]};
    const float* cb1[3] = {(const float*)d_in[10], (const float*)d_in[14], (const float*)d_in[18]};
    const float* cW2[3] = {(const float*)d_in[11], (const float*)d_in[15], (const float*)d_in[19]};
    const float* cb2[3] = {(const float*)d_in[12], (const float*)d_in[16], (const float*)d_in[20]};
    const float* d1W = (const float*)d_in[21];
    const float* d1b = (const float*)d_in[22];
    const float* d2W = (const float*)d_in[23];
    const float* d2b = (const float*)d_in[24];
    const float* oW  = (const float*)d_in[25];
    const float* ob  = (const float*)d_in[26];

    const int* src = eidx;
    const int* dst = eidx + N_EDGES;

    // workspace layout (srcs padded +64 ints, rec padded +8 records for the
    // full-chunk loads in k_gen_agg; pads zeroed/unused)
    char* p = (char*)d_ws;
    float* h      = (float*)p; p += (size_t)N_NODES * HD * 4;       // 25.6 MB
    float* outb   = (float*)p; p += (size_t)N_NODES * HD * 4;       // 25.6 MB
    int*   srcs   = (int*)p;   p += (size_t)(N_EDGES + 64) * 4;     // 6.4 MB + pad
    unsigned int* rec = (unsigned int*)p; p += (size_t)(N_EDGES + 8) * F_EDGE * 4; // 51.2 MB + pad
    u16*   hb     = (u16*)p;   p += (size_t)N_NODES * HD * 2;       // 12.8 MB
    float* pooled = (float*)p; p += (size_t)N_GRAPHS * HD * 4;
    int*   off    = (int*)p;   p += (size_t)(N_NODES + 1) * 4;
    int*   deg    = (int*)p;   p += (size_t)N_NODES * 4;
    int*   rank   = (int*)p;   p += (size_t)N_EDGES * 4;            // 6.4 MB
    int*   bsum   = (int*)p;   p += (size_t)(SCAN_NBLK + 1) * 4;
    int*   bpre   = (int*)p;   p += (size_t)(SCAN_NBLK + 1) * 4;

    const int EB = (N_EDGES + 255) / 256;
    const int NBM = (N_NODES + 63) / 64;   // 1563 MFMA blocks (64 nodes each)

    k_node_embed<<<(N_NODES * HD + 255) / 256, 256, 0, stream>>>(x, nodeW, nodeb, h, hb);

    // CSR build (atomic-free scatter via hist-captured ranks)
    hipMemsetAsync(deg, 0, (size_t)N_NODES * 4, stream);
    hipMemsetAsync(srcs + N_EDGES, 0, 64 * sizeof(int), stream);   // valid pad
    k_hist<<<EB, 256, 0, stream>>>(dst, deg, rank);
    k_scan1<<<SCAN_NBLK, 256, 0, stream>>>(deg, bsum);
    k_scan2<<<1, 512, 0, stream>>>(bsum, bpre);
    k_scan3<<<SCAN_NBLK, 256, 0, stream>>>(deg, bpre, off);
    k_scatter<<<EB, 256, 0, stream>>>(src, dst, rank, off, eattr, rec, srcs);

    for (int l = 0; l < 3; l++) {
        k_gen_agg<<<AGG_BLK, 256, 0, stream>>>(
            h, hb, off, rec, srcs, edgeW, edgeb, outb);
        k_mlp<<<NBM, 256, 0, stream>>>(outb, cW1[l], cb1[l], cW2[l], cb2[l], h, hb);
    }

    k_pool<<<(N_GRAPHS + 3) / 4, 256, 0, stream>>>(h, batch, pooled);
    k_head<<<N_GRAPHS, 64, 0, stream>>>(pooled, gattr,
                                        d1W, d1b, d2W, d2b, oW, ob,
                                        (float*)d_out);
}

// Round 5
// 698.910 us; speedup vs baseline: 1.4833x; 1.4833x over previous
//
#include <hip/hip_runtime.h>
#include <hip/hip_bf16.h>

#define N_NODES 100000
#define N_EDGES 1600000
#define N_GRAPHS 1024
#define F_NODE 16
#define F_EDGE 8
#define F_GRAPH 10
#define HD 64
#define HD2 128
#define GEN_EPS 1e-7f
#define SCAN_NBLK ((N_NODES + 255) / 256)   // 391

typedef unsigned short u16;
typedef unsigned int u32;
typedef __attribute__((ext_vector_type(8))) short short8;
typedef __attribute__((ext_vector_type(4))) float floatx4;

__device__ __forceinline__ u16 f2bf(float x) {   // RNE bf16 (finite inputs)
    u32 u = __float_as_uint(x);
    return (u16)((u + 0x7FFFu + ((u >> 16) & 1u)) >> 16);
}
__device__ __forceinline__ float bf2f(u16 u) {
    return __uint_as_float(((u32)u) << 16);
}
__device__ __forceinline__ float u2f(unsigned int u) {
    return __uint_as_float(u);
}

// h[n][f] = node_b[f] + sum_k x[n][k]*node_W[k][f]; also emits bf16 mirror hb.
__global__ void __launch_bounds__(256) k_node_embed(
        const float* __restrict__ x, const float* __restrict__ W,
        const float* __restrict__ b, float* __restrict__ h,
        u16* __restrict__ hb) {
    __shared__ float sW[F_NODE * HD];
    __shared__ float sb[HD];
    for (int i = threadIdx.x; i < F_NODE * HD; i += 256) sW[i] = W[i];
    if (threadIdx.x < HD) sb[threadIdx.x] = b[threadIdx.x];
    __syncthreads();
    int t = blockIdx.x * 256 + threadIdx.x;
    if (t >= N_NODES * HD) return;
    int n = t >> 6, f = t & 63;
    const float* xr = x + (size_t)n * F_NODE;
    float acc = sb[f];
#pragma unroll
    for (int k = 0; k < F_NODE; k++) acc += xr[k] * sW[k * HD + f];
    h[t] = acc;
    hb[t] = f2bf(acc);
}

// ---- CSR build ----
__global__ void __launch_bounds__(256) k_hist(
        const int* __restrict__ dst, int* __restrict__ deg,
        int* __restrict__ rank) {
    int e = blockIdx.x * 256 + threadIdx.x;
    if (e >= N_EDGES) return;
    rank[e] = atomicAdd(&deg[dst[e]], 1);
}

__global__ void __launch_bounds__(256) k_scan1(
        const int* __restrict__ deg, int* __restrict__ bsum) {
    __shared__ int red[256];
    int t = threadIdx.x;
    int g = blockIdx.x * 256 + t;
    red[t] = (g < N_NODES) ? deg[g] : 0;
    __syncthreads();
    for (int s = 128; s > 0; s >>= 1) {
        if (t < s) red[t] += red[t + s];
        __syncthreads();
    }
    if (t == 0) bsum[blockIdx.x] = red[0];
}

__global__ void __launch_bounds__(512) k_scan2(
        const int* __restrict__ bsum, int* __restrict__ bpre) {
    __shared__ int sh[512];
    int t = threadIdx.x;
    int v = (t < SCAN_NBLK) ? bsum[t] : 0;
    sh[t] = v;
    __syncthreads();
    for (int d = 1; d < 512; d <<= 1) {
        int u = (t >= d) ? sh[t - d] : 0;
        __syncthreads();
        sh[t] += u;
        __syncthreads();
    }
    if (t < SCAN_NBLK) bpre[t] = sh[t] - v;   // exclusive
}

__global__ void __launch_bounds__(256) k_scan3(
        const int* __restrict__ deg, const int* __restrict__ bpre,
        int* __restrict__ off) {
    __shared__ int sh[256];
    int t = threadIdx.x;
    int g = blockIdx.x * 256 + t;
    int v = (g < N_NODES) ? deg[g] : 0;
    sh[t] = v;
    __syncthreads();
    for (int d = 1; d < 256; d <<= 1) {
        int u = (t >= d) ? sh[t - d] : 0;
        __syncthreads();
        sh[t] += u;
        __syncthreads();
    }
    int incl = sh[t];
    int base = bpre[blockIdx.x];
    if (g < N_NODES) off[g] = base + incl - v;
    if (g == N_NODES - 1) off[N_NODES] = base + incl;
}

// Scatter edge attrs (verbatim) + separate srcs[] array.
__global__ void __launch_bounds__(256) k_scatter(
        const int* __restrict__ src, const int* __restrict__ dst,
        const int* __restrict__ rank, const int* __restrict__ off,
        const float* __restrict__ eattr,
        unsigned int* __restrict__ rec, int* __restrict__ srcs) {
    int e = blockIdx.x * 256 + threadIdx.x;
    if (e >= N_EDGES) return;
    const uint4* ap = reinterpret_cast<const uint4*>(eattr + (size_t)e * F_EDGE);
    uint4 a0 = ap[0], a1 = ap[1];           // coalesced 32B read
    int pos = off[dst[e]] + rank[e];
    uint4* op = reinterpret_cast<uint4*>(rec + (size_t)pos * 8);
    op[0] = a0;                              // one 32B sector
    op[1] = a1;
    srcs[pos] = src[e];
}

// ---- GENConv aggregation (round-2 structure, rec via VMEM + LDS broadcast) ----
// One wave per destination node (lane = feature), grid-stride persistent.
// Per 8-edge chunk:
//   - rec attrs: ONE per-lane coalesced global_load_dword (lane = 8u+k -> 256B)
//     staged to LDS via ds_write_b32; compute reads them back with uniform-
//     address ds_read_b128 broadcasts (2 per edge). This keeps the 51.2MB/layer
//     rec stream OFF the per-CU scalar cache (round-2's hidden serializer) and
//     off the readlane path (round-3's VALU sink).
//   - srcs: uniform s_load (6.4MB/layer, negligible sK$ traffic); gathers for
//     the whole chunk issued in a batch before compute.
//   - one-chunk software pipeline: next chunk's rec load + srcs s_loads issue
//     before current chunk's compute.
// VGPR budget kept <=64 (round-4 lesson: 68 VGPR -> 4 waves/SIMD -> 2x slower).
__global__ void __launch_bounds__(256) k_gen_agg(
        const float* __restrict__ h, const u16* __restrict__ hb,
        const int* __restrict__ off,
        const unsigned int* __restrict__ rec,
        const int* __restrict__ srcs,
        const float* __restrict__ eW, const float* __restrict__ eb,
        float* __restrict__ outb) {
    __shared__ float sAttr[4][64];          // per-wave chunk staging, 1KB
    int wid = threadIdx.x >> 6;
    int lane = threadIdx.x & 63;
    int f = lane;
    float w[F_EDGE];
#pragma unroll
    for (int k = 0; k < F_EDGE; k++) w[k] = eW[k * HD + f];
    float bf = eb[f];
    int wave0 = blockIdx.x * 4 + wid;
    const int NW = gridDim.x * 4;
    for (int n0 = wave0; n0 < N_NODES; n0 += NW) {
        int n = __builtin_amdgcn_readfirstlane(n0);
        int beg = off[n], end = off[n + 1];
        size_t idx = (size_t)n * HD + f;
        float hroot = h[idx];                 // hoisted; overlaps edge loop
        float den = 0.f, nm = 0.f;
        if (beg < end) {
            int i = beg;
            // prologue: chunk-0 rec (per-lane, guarded) + srcs (uniform s_load;
            // srcs has +64 zeroed pad so overrun reads are safe)
            float av = 0.f;
            if (beg + (lane >> 3) < end) av = u2f(rec[(size_t)beg * 8 + lane]);
            int s8[8];
#pragma unroll
            for (int u = 0; u < 8; u++) s8[u] = srcs[beg + u];
            while (true) {
                // batch-issue gathers for current chunk (pad srcs=0 -> hb[0..],
                // valid memory; results masked out in compute)
                float hv[8];
#pragma unroll
                for (int u = 0; u < 8; u++)
                    hv[u] = bf2f(hb[(size_t)s8[u] * HD + f]);
                // prefetch next chunk while gathers are in flight
                int inx = i + 8;
                bool more = inx < end;
                float avN = 0.f;
                int s8N[8];
                if (more) {
                    if (inx + (lane >> 3) < end)
                        avN = u2f(rec[(size_t)inx * 8 + lane]);
#pragma unroll
                    for (int u = 0; u < 8; u++) s8N[u] = srcs[inx + u];
                } else {
#pragma unroll
                    for (int u = 0; u < 8; u++) s8N[u] = 0;
                }
                // stage current chunk's attrs to LDS (same wave: no barrier)
                sAttr[wid][lane] = av;
#pragma unroll
                for (int u = 0; u < 8; u++) {
                    if (i + u < end) {       // uniform guard
                        const floatx4* A = reinterpret_cast<const floatx4*>(
                            &sAttr[wid][u * 8]);
                        floatx4 a0 = A[0], a1 = A[1];   // broadcast ds_read_b128
                        float ea = bf + a0.x * w[0] + a0.y * w[1]
                                      + a0.z * w[2] + a0.w * w[3]
                                      + a1.x * w[4] + a1.y * w[5]
                                      + a1.z * w[6] + a1.w * w[7];
                        float r = fmaxf(hv[u] + ea, 0.f);
                        float ev = __expf(r);
                        den += ev;
                        nm += r * ev;
                    }
                }
                if (!more) break;
                i = inx;
                av = avN;
#pragma unroll
                for (int u = 0; u < 8; u++) s8[u] = s8N[u];
            }
        }
        float agg = (end > beg) ? (nm / fmaxf(den, 1e-16f) + GEN_EPS) : 0.f;
        outb[idx] = hroot + agg;
    }
}

// ---- Fused MLP (MFMA): hid = relu(in@W1+b1) staged in LDS, then
// h' = relu(hid@W2+b2). Kills the 25.6MB x2 global round-trip per layer.
// Layouts identical to the previously-verified split kernels:
// A[m=lane&15][k=quad*8+j], B[n=lane&15][k=quad*8+j], D col=lane&15 row=quad*4+r.
__global__ void __launch_bounds__(256) k_mlp(
        const float* __restrict__ inb,
        const float* __restrict__ W1, const float* __restrict__ b1,
        const float* __restrict__ W2, const float* __restrict__ b2,
        float* __restrict__ hout, u16* __restrict__ hbout) {
    __shared__ u16 wB1[HD2][HD + 8];    // [j][k], 18.4 KB
    __shared__ u16 wB2[HD][HD2 + 8];    // [c][j], 17.4 KB
    __shared__ u16 sHid[64][HD2 + 8];   // [local n][j], 17.4 KB
    __shared__ float sb1[HD2];
    __shared__ float sb2[HD];
    int tid = threadIdx.x;
    for (int i = tid; i < HD * HD2; i += 256) {
        int ff = i >> 7, j = i & 127;
        wB1[j][ff] = f2bf(W1[i]);
    }
    for (int i = tid; i < HD2 * HD; i += 256) {
        int j = i >> 6, c = i & 63;
        wB2[c][j] = f2bf(W2[i]);
    }
    if (tid < HD2) sb1[tid] = b1[tid];
    if (tid < HD) sb2[tid] = b2[tid];
    __syncthreads();
    int wid = tid >> 6, lane = tid & 63;
    int quad = lane >> 4, lm = lane & 15;
    int n0 = blockIdx.x * 64 + wid * 16;
    bool active = (n0 < N_NODES);         // 100000 % 16 == 0: whole-tile guard
    if (active) {
        int node = n0 + lm;
        short8 a[2];
        const float* ar = inb + (size_t)node * HD;
#pragma unroll
        for (int kk = 0; kk < 2; kk++) {
            const float4* p = reinterpret_cast<const float4*>(ar + kk * 32 + quad * 8);
            float4 v0 = p[0], v1 = p[1];
            short8 t;
            t[0] = (short)f2bf(v0.x); t[1] = (short)f2bf(v0.y);
            t[2] = (short)f2bf(v0.z); t[3] = (short)f2bf(v0.w);
            t[4] = (short)f2bf(v1.x); t[5] = (short)f2bf(v1.y);
            t[6] = (short)f2bf(v1.z); t[7] = (short)f2bf(v1.w);
            a[kk] = t;
        }
#pragma unroll
        for (int jt = 0; jt < 8; jt++) {
            int jb = jt * 16;
            float bias = sb1[jb + lm];
            floatx4 acc = {bias, bias, bias, bias};
#pragma unroll
            for (int kk = 0; kk < 2; kk++) {
                const short8* bp = reinterpret_cast<const short8*>(
                    &wB1[jb + lm][kk * 32 + quad * 8]);
                acc = __builtin_amdgcn_mfma_f32_16x16x32_bf16(a[kk], *bp, acc, 0, 0, 0);
            }
#pragma unroll
            for (int r = 0; r < 4; r++) {
                int lr = wid * 16 + quad * 4 + r;
                sHid[lr][jb + lm] = f2bf(fmaxf(acc[r], 0.f));
            }
        }
    }
    __syncthreads();
    if (active) {
        short8 a2[4];
#pragma unroll
        for (int kk = 0; kk < 4; kk++)
            a2[kk] = *reinterpret_cast<const short8*>(
                &sHid[wid * 16 + lm][kk * 32 + quad * 8]);
#pragma unroll
        for (int ct = 0; ct < 4; ct++) {
            int cb = ct * 16;
            float bias = sb2[cb + lm];
            floatx4 acc = {bias, bias, bias, bias};
#pragma unroll
            for (int kk = 0; kk < 4; kk++) {
                const short8* bp = reinterpret_cast<const short8*>(
                    &wB2[cb + lm][kk * 32 + quad * 8]);
                acc = __builtin_amdgcn_mfma_f32_16x16x32_bf16(a2[kk], *bp, acc, 0, 0, 0);
            }
#pragma unroll
            for (int r = 0; r < 4; r++) {
                int orow = n0 + quad * 4 + r;
                float o = fmaxf(acc[r], 0.f);
                hout[(size_t)orow * HD + cb + lm] = o;
                hbout[(size_t)orow * HD + cb + lm] = f2bf(o);
            }
        }
    }
}

// One wave per graph; range via inline binary search on sorted batch.
__global__ void __launch_bounds__(256) k_pool(
        const float* __restrict__ h, const int* __restrict__ batch,
        float* __restrict__ pooled) {
    int g = blockIdx.x * 4 + (threadIdx.x >> 6);
    if (g >= N_GRAPHS) return;
    int f = threadIdx.x & 63;
    int lo = 0, hi = N_NODES;
    while (lo < hi) {
        int mid = (lo + hi) >> 1;
        if (batch[mid] < g) lo = mid + 1; else hi = mid;
    }
    int b = lo;
    int lo2 = b, hi2 = N_NODES;
    while (lo2 < hi2) {
        int mid = (lo2 + hi2) >> 1;
        if (batch[mid] < g + 1) lo2 = mid + 1; else hi2 = mid;
    }
    int e = lo2;
    float s = 0.f;
    for (int n = b; n < e; n++) s += h[(size_t)n * HD + f];
    float cnt = fmaxf((float)(e - b), 1.f);
    pooled[(size_t)g * HD + f] = s / cnt;
}

__global__ void __launch_bounds__(64) k_head(
        const float* __restrict__ pooled, const float* __restrict__ gattr,
        const float* __restrict__ d1W, const float* __restrict__ d1b,
        const float* __restrict__ d2W, const float* __restrict__ d2b,
        const float* __restrict__ oW, const float* __restrict__ ob,
        float* __restrict__ out) {
    int g = blockIdx.x;
    __shared__ float si[HD + F_GRAPH];
    __shared__ float s1[32], s2[32];
    int t = threadIdx.x;
    if (t < HD) si[t] = pooled[(size_t)g * HD + t];
    if (t < F_GRAPH) si[HD + t] = gattr[(size_t)g * F_GRAPH + t];
    __syncthreads();
    if (t < 32) {
        float acc = d1b[t];
        for (int i = 0; i < HD + F_GRAPH; i++) acc += si[i] * d1W[i * 32 + t];
        s1[t] = fmaxf(acc, 0.f);
    }
    __syncthreads();
    if (t < 32) {
        float acc = d2b[t];
        for (int i = 0; i < 32; i++) acc += s1[i] * d2W[i * 32 + t];
        s2[t] = fmaxf(acc, 0.f);
    }
    __syncthreads();
    if (t == 0) {
        float acc = ob[0];
        for (int i = 0; i < 32; i++) acc += s2[i] * oW[i];
        out[g] = 1.f / (1.f + __expf(-acc));
    }
}

extern "C" void kernel_launch(void* const* d_in, const int* in_sizes, int n_in,
                              void* d_out, int out_size, void* d_ws, size_t ws_size,
                              hipStream_t stream) {
    const float* x     = (const float*)d_in[0];
    const float* eattr = (const float*)d_in[1];
    const float* gattr = (const float*)d_in[2];
    const int*   eidx  = (const int*)d_in[3];
    const int*   batch = (const int*)d_in[4];
    const float* nodeW = (const float*)d_in[5];
    const float* nodeb = (const float*)d_in[6];
    const float* edgeW = (const float*)d_in[7];
    const float* edgeb = (const float*)d_in[8];
    const float* cW1[3] = {(const float*)d_in[9],  (const float*)d_in[13], (const float*)d_in[17]};
    const float* cb1[3] = {(const float*)d_in[10], (const float*)d_in[14], (const float*)d_in[18]};
    const float* cW2[3] = {(const float*)d_in[11], (const float*)d_in[15], (const float*)d_in[19]};
    const float* cb2[3] = {(const float*)d_in[12], (const float*)d_in[16], (const float*)d_in[20]};
    const float* d1W = (const float*)d_in[21];
    const float* d1b = (const float*)d_in[22];
    const float* d2W = (const float*)d_in[23];
    const float* d2b = (const float*)d_in[24];
    const float* oW  = (const float*)d_in[25];
    const float* ob  = (const float*)d_in[26];

    const int* src = eidx;
    const int* dst = eidx + N_EDGES;

    // workspace layout (srcs padded +64 ints (zeroed), rec padded +8 records
    // for the chunked loads in k_gen_agg)
    char* p = (char*)d_ws;
    float* h      = (float*)p; p += (size_t)N_NODES * HD * 4;       // 25.6 MB
    float* outb   = (float*)p; p += (size_t)N_NODES * HD * 4;       // 25.6 MB
    int*   srcs   = (int*)p;   p += (size_t)(N_EDGES + 64) * 4;     // 6.4 MB + pad
    unsigned int* rec = (unsigned int*)p; p += (size_t)(N_EDGES + 8) * F_EDGE * 4; // 51.2 MB + pad
    u16*   hb     = (u16*)p;   p += (size_t)N_NODES * HD * 2;       // 12.8 MB
    float* pooled = (float*)p; p += (size_t)N_GRAPHS * HD * 4;
    int*   off    = (int*)p;   p += (size_t)(N_NODES + 1) * 4;
    int*   deg    = (int*)p;   p += (size_t)N_NODES * 4;
    int*   rank   = (int*)p;   p += (size_t)N_EDGES * 4;            // 6.4 MB
    int*   bsum   = (int*)p;   p += (size_t)(SCAN_NBLK + 1) * 4;
    int*   bpre   = (int*)p;   p += (size_t)(SCAN_NBLK + 1) * 4;

    const int EB = (N_EDGES + 255) / 256;
    const int NBM = (N_NODES + 63) / 64;   // 1563 MFMA blocks (64 nodes each)

    k_node_embed<<<(N_NODES * HD + 255) / 256, 256, 0, stream>>>(x, nodeW, nodeb, h, hb);

    // CSR build (atomic-free scatter via hist-captured ranks)
    hipMemsetAsync(deg, 0, (size_t)N_NODES * 4, stream);
    hipMemsetAsync(srcs + N_EDGES, 0, 64 * sizeof(int), stream);   // valid pad
    k_hist<<<EB, 256, 0, stream>>>(dst, deg, rank);
    k_scan1<<<SCAN_NBLK, 256, 0, stream>>>(deg, bsum);
    k_scan2<<<1, 512, 0, stream>>>(bsum, bpre);
    k_scan3<<<SCAN_NBLK, 256, 0, stream>>>(deg, bpre, off);
    k_scatter<<<EB, 256, 0, stream>>>(src, dst, rank, off, eattr, rec, srcs);

    for (int l = 0; l < 3; l++) {
        k_gen_agg<<<2048, 256, 0, stream>>>(
            h, hb, off, rec, srcs, edgeW, edgeb, outb);
        k_mlp<<<NBM, 256, 0, stream>>>(outb, cW1[l], cb1[l], cW2[l], cb2[l], h, hb);
    }

    k_pool<<<(N_GRAPHS + 3) / 4, 256, 0, stream>>>(h, batch, pooled);
    k_head<<<N_GRAPHS, 64, 0, stream>>>(pooled, gattr,
                                        d1W, d1b, d2W, d2b, oW, ob,
                                        (float*)d_out);
}